// Round 10
// baseline (275.397 us; speedup 1.0000x reference)
//
#include <hip/hip_runtime.h>

#define B_     256
#define NI_    1152
#define NO_    10
#define DO_    16
#define DI_    8
#define PAIRS_ 160
#define SEGS_  128
#define ISEG_  (NI_/SEGS_)  // 9
#define PSV_   4            // pair splits (blocks)
#define PPW_   10           // pairs per wave (4 ps x 4 waves x 10 = 160)

// ===================== fast path =====================

// Tiled transpose x[b,d,i] -> xT[(i*8+d)*256+b]; tail blocks init blog/cmat.
__global__ __launch_bounds__(256) void prep_kernel(const float* __restrict__ x,
                                                   float* __restrict__ xT,
                                                   float* __restrict__ blog,
                                                   float* __restrict__ cmat)
{
    int vb = blockIdx.x;
    int tid = threadIdx.x, lane = tid & 63, wv = tid >> 6;
    if (vb < 576) {                         // (d, b-tile, i-tile): 8 x 4 x 18
        __shared__ float tile[64 * 65];
        int d = vb & 7, rest = vb >> 3, tb = rest & 3, ti = rest >> 2;
        int i0 = ti * 64, b0 = tb * 64;
#pragma unroll
        for (int k = 0; k < 16; ++k) {      // read: lanes over i (coalesced)
            int bL = wv * 16 + k;
            tile[bL * 65 + lane] = x[(size_t)(b0 + bL) * (NI_ * DI_) + d * NI_ + i0 + lane];
        }
        __syncthreads();
#pragma unroll
        for (int k = 0; k < 16; ++k) {      // write: lanes over b (coalesced)
            int iL = wv * 16 + k;
            xT[((size_t)(i0 + iL) * DI_ + d) * B_ + b0 + lane] = tile[lane * 65 + iL];
        }
    } else {
        int g = (vb - 576) * 256 + tid;     // 45 blocks cover 11520
        if (g < NI_ * NO_) { blog[g] = 0.f; cmat[g] = 0.1f; }
    }
}

// Grid (seg 0..127, ps 0..3): linear%8 = seg%8 -> the 4 ps-blocks sharing a seg's
// x rows land on the SAME XCD (L2 locality for the duplicated reads).
// 4 waves/block, wave handles 10 pairs x all 256 b (4/thread, float4).
// x register-prefetched one i ahead; W/cmat wave-uniform -> s_load.
__global__ __launch_bounds__(256, 2) void sv_kernel(const float* __restrict__ xT,
                                                    const float* __restrict__ W,
                                                    const float* __restrict__ cmat,
                                                    float* __restrict__ partial)
{
    int seg  = blockIdx.x;
    int ps   = blockIdx.y;
    int tid  = threadIdx.x;
    int lane = tid & 63;
    int wv   = __builtin_amdgcn_readfirstlane(tid >> 6);
    int p0   = ps * (4 * PPW_) + wv * PPW_;
    int b0   = lane * 4;
    int i0   = seg * ISEG_;

    float acc[PPW_][4];
#pragma unroll
    for (int p = 0; p < PPW_; ++p)
#pragma unroll
        for (int r = 0; r < 4; ++r) acc[p][r] = 0.f;

    float4 nx[DI_];
#pragma unroll
    for (int d = 0; d < DI_; ++d)
        nx[d] = *(const float4*)&xT[((size_t)i0 * DI_ + d) * B_ + b0];

#pragma unroll
    for (int ii = 0; ii < ISEG_; ++ii) {    // compile-time 9: fully unrolled,
        int i = i0 + ii;                    // cx/nx copies renamed away
        float4 cx[DI_];
#pragma unroll
        for (int d = 0; d < DI_; ++d) cx[d] = nx[d];
        if (ii + 1 < ISEG_) {
#pragma unroll
            for (int d = 0; d < DI_; ++d)
                nx[d] = *(const float4*)&xT[((size_t)(i + 1) * DI_ + d) * B_ + b0];
        }
        const float* __restrict__ crow = cmat + i * NO_;                      // uniform
        const float* __restrict__ wb   = W + (size_t)(i * PAIRS_ + p0) * DI_; // uniform
#pragma unroll
        for (int p = 0; p < PPW_; ++p) {
            const float* wr = wb + p * DI_;                                   // s_load x8
            float cv = crow[(p0 + p) >> 4];
            float u0 = wr[0] * cx[0].x, u1 = wr[0] * cx[0].y;
            float u2 = wr[0] * cx[0].z, u3 = wr[0] * cx[0].w;
#pragma unroll
            for (int d = 1; d < DI_; ++d) {
                u0 = fmaf(wr[d], (&cx[d].x)[0], u0);
                u1 = fmaf(wr[d], (&cx[d].x)[1], u1);
                u2 = fmaf(wr[d], (&cx[d].x)[2], u2);
                u3 = fmaf(wr[d], (&cx[d].x)[3], u3);
            }
            acc[p][0] = fmaf(cv, u0, acc[p][0]);
            acc[p][1] = fmaf(cv, u1, acc[p][1]);
            acc[p][2] = fmaf(cv, u2, acc[p][2]);
            acc[p][3] = fmaf(cv, u3, acc[p][3]);
        }
    }
#pragma unroll
    for (int p = 0; p < PPW_; ++p)
        *(float4*)&partial[(size_t)(seg * PAIRS_ + p0 + p) * B_ + b0] =
            make_float4(acc[p][0], acc[p][1], acc[p][2], acc[p][3]);
}

// Fused reduce+squash: grid (10 j, 16 b-chunks); thread = (o, b_l 16).
__global__ __launch_bounds__(256) void red_kernel(const float* __restrict__ partial,
                                                  float* __restrict__ vbuf,
                                                  float* __restrict__ out,
                                                  int write_out)
{
    int j   = blockIdx.x;
    int bc  = blockIdx.y;
    int o   = threadIdx.x >> 4;
    int b_l = threadIdx.x & 15;
    int b   = bc * 16 + b_l;
    int pair = j * DO_ + o;

    float s = 0.f;
    for (int seg = 0; seg < SEGS_; ++seg)
        s += partial[(size_t)(seg * PAIRS_ + pair) * B_ + b];

    __shared__ float so[DO_][17];
    so[o][b_l] = s;
    __syncthreads();
    float sq = 0.f;
#pragma unroll
    for (int oo = 0; oo < DO_; ++oo) { float t = so[oo][b_l]; sq = fmaf(t, t, sq); }
    float f = (sq / (1.f + sq)) * rsqrtf(sq + 1e-9f);
    float vv = s * f;
    vbuf[pair * B_ + b] = vv;
    if (write_out) out[(size_t)b * PAIRS_ + pair] = vv;
}

// Block = 2 input capsules (i0, i0+1): vbuf float4 loads shared across both i's.
// Agreement update AND next-iter softmax fused. W s_load, xT/vbuf coalesced.
__global__ __launch_bounds__(256, 2) void agree_kernel(const float* __restrict__ xT,
                                                       const float* __restrict__ W,
                                                       const float* __restrict__ vbuf,
                                                       float* __restrict__ blog,
                                                       float* __restrict__ cmat)
{
    int i0   = blockIdx.x * 2;
    int lane = threadIdx.x & 63;
    int wv   = __builtin_amdgcn_readfirstlane(threadIdx.x >> 6);
    int b0   = lane * 4;

    float xv0[DI_][4], xv1[DI_][4];
#pragma unroll
    for (int d = 0; d < DI_; ++d) {
        float4 a = *(const float4*)&xT[((size_t)i0 * DI_ + d) * B_ + b0];
        float4 c = *(const float4*)&xT[((size_t)(i0 + 1) * DI_ + d) * B_ + b0];
        xv0[d][0] = a.x; xv0[d][1] = a.y; xv0[d][2] = a.z; xv0[d][3] = a.w;
        xv1[d][0] = c.x; xv1[d][1] = c.y; xv1[d][2] = c.z; xv1[d][3] = c.w;
    }
    __shared__ float js[2][NO_];
    __shared__ float nbs[2][NO_];
    for (int j = wv; j < NO_; j += 4) {                       // wave-uniform
        const float* __restrict__ wj0 = W + (size_t)(i0 * NO_ + j) * DO_ * DI_;
        const float* __restrict__ wj1 = W + (size_t)((i0 + 1) * NO_ + j) * DO_ * DI_;
        float aj0 = 0.f, aj1 = 0.f;
#pragma unroll
        for (int o = 0; o < DO_; ++o) {
            const float* wr0 = wj0 + o * DI_;                               // s_load x8
            const float* wr1 = wj1 + o * DI_;                               // s_load x8
            float4 vv4 = *(const float4*)&vbuf[(j * DO_ + o) * B_ + b0];    // shared load
            float u0 = wr0[0] * xv0[0][0], u1 = wr0[0] * xv0[0][1];
            float u2 = wr0[0] * xv0[0][2], u3 = wr0[0] * xv0[0][3];
            float w0 = wr1[0] * xv1[0][0], w1 = wr1[0] * xv1[0][1];
            float w2 = wr1[0] * xv1[0][2], w3 = wr1[0] * xv1[0][3];
#pragma unroll
            for (int d = 1; d < DI_; ++d) {
                u0 = fmaf(wr0[d], xv0[d][0], u0); u1 = fmaf(wr0[d], xv0[d][1], u1);
                u2 = fmaf(wr0[d], xv0[d][2], u2); u3 = fmaf(wr0[d], xv0[d][3], u3);
                w0 = fmaf(wr1[d], xv1[d][0], w0); w1 = fmaf(wr1[d], xv1[d][1], w1);
                w2 = fmaf(wr1[d], xv1[d][2], w2); w3 = fmaf(wr1[d], xv1[d][3], w3);
            }
            aj0 = fmaf(u0, vv4.x, aj0); aj0 = fmaf(u1, vv4.y, aj0);
            aj0 = fmaf(u2, vv4.z, aj0); aj0 = fmaf(u3, vv4.w, aj0);
            aj1 = fmaf(w0, vv4.x, aj1); aj1 = fmaf(w1, vv4.y, aj1);
            aj1 = fmaf(w2, vv4.z, aj1); aj1 = fmaf(w3, vv4.w, aj1);
        }
        for (int off = 32; off > 0; off >>= 1) {
            aj0 += __shfl_down(aj0, off);
            aj1 += __shfl_down(aj1, off);
        }
        if (lane == 0) { js[0][j] = aj0; js[1][j] = aj1; }
    }
    __syncthreads();
    if (threadIdx.x < 2 * NO_) {
        int ii = threadIdx.x / NO_, j = threadIdx.x % NO_;
        float nb = blog[(i0 + ii) * NO_ + j] + js[ii][j] * (1.f / B_);
        blog[(i0 + ii) * NO_ + j] = nb;
        nbs[ii][j] = nb;
    }
    __syncthreads();
    if (threadIdx.x < 2 * NO_) {
        int ii = threadIdx.x / NO_, j = threadIdx.x % NO_;
        float m = nbs[ii][0];
#pragma unroll
        for (int k = 1; k < NO_; ++k) m = fmaxf(m, nbs[ii][k]);
        float ssum = 0.f;
#pragma unroll
        for (int k = 0; k < NO_; ++k) ssum += __expf(nbs[ii][k] - m);
        cmat[(i0 + ii) * NO_ + j] = __expf(nbs[ii][j] - m) / ssum;
    }
}

// ===================== fallback path (proven R4 kernels, small ws) =====================

__global__ __launch_bounds__(256) void c_old(float* __restrict__ blog,
                                             float* __restrict__ cmat, int init)
{
    int i = blockIdx.x * 256 + threadIdx.x;
    if (i >= NI_) return;
    if (init) {
#pragma unroll
        for (int j = 0; j < NO_; ++j) { cmat[i * NO_ + j] = 0.1f; blog[i * NO_ + j] = 0.f; }
        return;
    }
    float r[NO_]; float m = -1e30f;
#pragma unroll
    for (int j = 0; j < NO_; ++j) { r[j] = blog[i * NO_ + j]; m = fmaxf(m, r[j]); }
    float s = 0.f;
#pragma unroll
    for (int j = 0; j < NO_; ++j) { r[j] = __expf(r[j] - m); s += r[j]; }
    float inv = 1.f / s;
#pragma unroll
    for (int j = 0; j < NO_; ++j) cmat[i * NO_ + j] = r[j] * inv;
}

__global__ __launch_bounds__(640) void sv_old(const float* __restrict__ x,
                                              const float* __restrict__ W,
                                              const float* __restrict__ cmat,
                                              float* __restrict__ vbuf,
                                              float* __restrict__ out, int write_out)
{
    __shared__ __align__(16) float xL[NI_ * DI_];
    __shared__ float sred[4 * PAIRS_];
    __shared__ float sfin[PAIRS_];
    int b = blockIdx.x;
    {
        const float4* xs = (const float4*)(x + (size_t)b * NI_ * DI_);
        for (int t = threadIdx.x; t < NI_ * DI_ / 4; t += 640) {
            float4 v4 = xs[t];
            int f = 4 * t; int d = f / NI_; int i = f - d * NI_;
            xL[i * DI_ + d] = v4.x; xL[(i+1) * DI_ + d] = v4.y;
            xL[(i+2) * DI_ + d] = v4.z; xL[(i+3) * DI_ + d] = v4.w;
        }
    }
    __syncthreads();
    int pair = threadIdx.x % PAIRS_;
    int seg  = threadIdx.x / PAIRS_;
    int j    = pair >> 4;
    const float4* Wq = (const float4*)W;
    float acc = 0.f;
    int i0 = seg * (NI_ / 4);
    for (int i = i0; i < i0 + NI_ / 4; ++i) {
        float4 w0 = Wq[(i * PAIRS_ + pair) * 2];
        float4 w1 = Wq[(i * PAIRS_ + pair) * 2 + 1];
        const float* xp = &xL[i * DI_];
        float u = w0.x * xp[0] + w0.y * xp[1] + w0.z * xp[2] + w0.w * xp[3]
                + w1.x * xp[4] + w1.y * xp[5] + w1.z * xp[6] + w1.w * xp[7];
        acc = fmaf(cmat[i * NO_ + j], u, acc);
    }
    sred[threadIdx.x] = acc;
    __syncthreads();
    float s = 0.f;
    if (threadIdx.x < PAIRS_) {
        s = sred[threadIdx.x] + sred[PAIRS_ + threadIdx.x]
          + sred[2 * PAIRS_ + threadIdx.x] + sred[3 * PAIRS_ + threadIdx.x];
        sfin[threadIdx.x] = s;
    }
    __syncthreads();
    if (threadIdx.x < PAIRS_) {
        int jj = threadIdx.x >> 4;
        float sq = 0.f;
#pragma unroll
        for (int o = 0; o < DO_; ++o) { float t = sfin[(jj << 4) + o]; sq = fmaf(t, t, sq); }
        float vv = s * (sq / (1.f + sq)) * rsqrtf(sq + 1e-9f);
        vbuf[b * PAIRS_ + threadIdx.x] = vv;
        if (write_out) out[b * PAIRS_ + threadIdx.x] = vv;
    }
}

__global__ __launch_bounds__(256) void agree_old(const float* __restrict__ x,
                                                 const float* __restrict__ W,
                                                 const float* __restrict__ vbuf,
                                                 float* __restrict__ blog)
{
    int i = blockIdx.x;
    int b = threadIdx.x;
    float xr[DI_];
#pragma unroll
    for (int d = 0; d < DI_; ++d) xr[d] = x[((size_t)b * DI_ + d) * NI_ + i];
    __shared__ float red[4][NO_];
    int lane = threadIdx.x & 63;
    int wv   = threadIdx.x >> 6;
    for (int j = 0; j < NO_; ++j) {
        const float* vp = &vbuf[b * PAIRS_ + j * DO_];
        float aj = 0.f;
#pragma unroll
        for (int o = 0; o < DO_; ++o) {
            const float* wr = W + (size_t)((i * NO_ + j) * DO_ + o) * DI_;
            float u = wr[0] * xr[0] + wr[1] * xr[1] + wr[2] * xr[2] + wr[3] * xr[3]
                    + wr[4] * xr[4] + wr[5] * xr[5] + wr[6] * xr[6] + wr[7] * xr[7];
            aj = fmaf(u, vp[o], aj);
        }
        float val = aj;
        for (int off = 32; off > 0; off >>= 1) val += __shfl_down(val, off);
        if (lane == 0) red[wv][j] = val;
    }
    __syncthreads();
    if (threadIdx.x < NO_) {
        float sum = red[0][threadIdx.x] + red[1][threadIdx.x]
                  + red[2][threadIdx.x] + red[3][threadIdx.x];
        blog[i * NO_ + threadIdx.x] += sum * (1.f / B_);
    }
}

// ===================== launch =====================

extern "C" void kernel_launch(void* const* d_in, const int* in_sizes, int n_in,
                              void* d_out, int out_size, void* d_ws, size_t ws_size,
                              hipStream_t stream)
{
    const float* x = (const float*)d_in[0];   // [256,8,1152]
    const float* W = (const float*)d_in[1];   // [1152,10,16,8]
    float* out = (float*)d_out;               // [256,10,16]

    const size_t XT_N  = (size_t)NI_ * DI_ * B_;         // 2,359,296
    const size_t LOG_N = NI_ * NO_;                      // 11,520
    const size_t V_N   = PAIRS_ * B_;                    // 40,960
    const size_t P_N   = (size_t)SEGS_ * PAIRS_ * B_;    // 5,242,880
    const size_t NEED  = (XT_N + 2 * LOG_N + V_N + P_N) * sizeof(float);  // ~30.7 MB

    if (ws_size >= NEED) {
        float* xT      = (float*)d_ws;
        float* blog    = xT + XT_N;
        float* cmat    = blog + LOG_N;
        float* vbuf    = cmat + LOG_N;
        float* partial = vbuf + V_N;

        prep_kernel<<<576 + 45, 256, 0, stream>>>(x, xT, blog, cmat);
        for (int it = 0; it < 3; ++it) {
            sv_kernel<<<dim3(SEGS_, PSV_), 256, 0, stream>>>(xT, W, cmat, partial);
            red_kernel<<<dim3(NO_, B_ / 16), 256, 0, stream>>>(partial, vbuf, out,
                                                               it == 2 ? 1 : 0);
            if (it < 2) agree_kernel<<<NI_ / 2, 256, 0, stream>>>(xT, W, vbuf, blog, cmat);
        }
    } else {
        float* blog = (float*)d_ws;
        float* cmat = blog + LOG_N;
        float* vbuf = cmat + LOG_N;
        for (int it = 0; it < 3; ++it) {
            c_old<<<(NI_ + 255) / 256, 256, 0, stream>>>(blog, cmat, it == 0 ? 1 : 0);
            sv_old<<<B_, 640, 0, stream>>>(x, W, cmat, vbuf, out, it == 2 ? 1 : 0);
            if (it < 2) agree_old<<<NI_, 256, 0, stream>>>(x, W, vbuf, blog);
        }
    }
}